// Round 4
// baseline (269.045 us; speedup 1.0000x reference)
//
#include <hip/hip_runtime.h>

static constexpr int B_ = 256;
static constexpr int R_ = 1152;
static constexpr int C_ = 10;
static constexpr int O_ = 16;
static constexpr int I_ = 8;
static constexpr int SCO = C_ * O_;   // 160
static constexpr int K_ = R_ * I_;    // 9216
static constexpr int NB = 256;        // grid: = CU count, 1 block/CU via LDS

typedef short bf16x8 __attribute__((ext_vector_type(8)));
typedef float f32x4  __attribute__((ext_vector_type(4)));

__device__ __forceinline__ unsigned short f2bf(float f) {
  union { float f; unsigned int u; } c; c.f = f;
  const unsigned int u = c.u;
  return (unsigned short)((u + 0x7fffu + ((u >> 16) & 1u)) >> 16);  // RNE
}
__device__ __forceinline__ float bf2f(unsigned short h) {
  union { unsigned int u; float f; } c; c.u = ((unsigned int)h) << 16; return c.f;
}

// Manual grid barrier. KEY FIX vs r3: spin on RELAXED atomic loads (agent-scope
// atomics are coherent regardless of ordering; ordering only adds fences), then
// ONE acquire fence after the barrier. r3's ACQUIRE-load spin emitted
// buffer_inv (L1+L2) per poll -> continuous L2 invalidation storm from idle
// blocks, measured as 537 GB/s effective and 62 MB FETCH. Release side of the
// fetch_add still publishes (wbL2) this block's stores.
__device__ __forceinline__ void gsync(unsigned int* bar, unsigned int target) {
  __syncthreads();
  if (threadIdx.x == 0) {
    __hip_atomic_fetch_add(bar, 1u, __ATOMIC_RELEASE, __HIP_MEMORY_SCOPE_AGENT);
    int guard = 0;
    while (__hip_atomic_load(bar, __ATOMIC_RELAXED, __HIP_MEMORY_SCOPE_AGENT) < target) {
      __builtin_amdgcn_s_sleep(4);
      if (++guard > (1 << 22)) break;   // degrade to wrong answer, never hang
    }
  }
  __syncthreads();
  __builtin_amdgcn_fence(__ATOMIC_ACQUIRE, "agent");  // one invalidate per wave
}

// ===========================================================================
// mega: ONE plain launch, 256 blocks x 512 threads, 82.5 KB LDS (1 block/CU).
// Phases: prep -> [gemm(160 blks) -> pv(72 blks)] x2 -> gemm(final).
// All inter-phase buffers write-once-per-address per execution (vb/wb2
// ping-pong); Z accumulated/read via device-scope atomics.
// ===========================================================================
__global__ __launch_bounds__(512, 1) void mega(
    const float* __restrict__ x, const float* __restrict__ W,
    float* __restrict__ out, unsigned int* __restrict__ bar,
    float* __restrict__ bvec, float* __restrict__ Z,
    unsigned short* __restrict__ xb, unsigned short* __restrict__ wraw,
    unsigned short* __restrict__ xT,
    unsigned short* __restrict__ vb0, unsigned short* __restrict__ vb1,
    unsigned short* __restrict__ wb2a, unsigned short* __restrict__ wb2b) {
  __shared__ __align__(16) unsigned char smem[82560];
  const int bx = blockIdx.x;
  const int t = threadIdx.x;
  const int lane = t & 63;
  const int w = __builtin_amdgcn_readfirstlane(t >> 6);   // 0..7
  const int mrow = lane & 15, quad = lane >> 4;

  // ---------------- prep: W -> wraw; x -> xb + xT (LDS transpose) ----------
  {
    // W: 368640 float4 total = 1440 per block (exact)
    const float4* wf = (const float4*)W;
    ushort4* wr = (ushort4*)wraw;
    for (int idx = t; idx < 1440; idx += 512) {
      const int j = bx * 1440 + idx;
      const float4 v4 = wf[j];
      ushort4 r4;
      r4.x = f2bf(v4.x); r4.y = f2bf(v4.y); r4.z = f2bf(v4.z); r4.w = f2bf(v4.w);
      wr[j] = r4;
    }
    if (bx == 0 && t < 32) Z[t] = 0.0f;      // Z[10..29] accumulated by pv
    // x: 256 units of (64 b x 18 r), exactly one per block
    float* sx = (float*)smem;                // 144 x 68 floats = 39168 B
    const int bq = bx & 3, rseg = bx >> 2;
    const int rbase = rseg * 18;
    for (int idx = t; idx < 64 * 36; idx += 512) {
      const int b = idx / 36, f4 = idx - b * 36;
      const size_t off = (size_t)(bq * 64 + b) * K_ + rbase * I_ + f4 * 4;
      const float4 val = *(const float4*)(x + off);
      ushort4 o4;
      o4.x = f2bf(val.x); o4.y = f2bf(val.y); o4.z = f2bf(val.z); o4.w = f2bf(val.w);
      *(ushort4*)(xb + off) = o4;
      const int rr = f4 >> 1, i4 = (f4 & 1) * 4;
      sx[(rr * 8 + i4 + 0) * 68 + b] = val.x;
      sx[(rr * 8 + i4 + 1) * 68 + b] = val.y;
      sx[(rr * 8 + i4 + 2) * 68 + b] = val.z;
      sx[(rr * 8 + i4 + 3) * 68 + b] = val.w;
    }
    __syncthreads();
    for (int row = w * 18; row < w * 18 + 18; ++row)
      xT[(size_t)(rseg * 144 + row) * 256 + bq * 64 + lane] = f2bf(sx[row * 68 + lane]);
  }
  gsync(bar, NB);

  for (int it = 0; it < 3; ++it) {
    // ------------- gemm: 160 active blocks, full-K, 8-wave LDS reduce ------
    if (bx < 160) {
      float* sred = (float*)smem;            // 8 x 272 floats
      float* szed = (float*)(smem + 16384);  // 10 floats
      const unsigned short* Bm = (it == 0) ? wraw : (it == 1 ? wb2a : wb2b);
      const int g = (bx & 7) * 20 + (bx >> 3);  // XCD: 2 mtiles x 10 c (3.5 MB)
      const int mtile = g / 10, c = g - mtile * 10;
      const int m0 = mtile * 16;
      const unsigned short* ap = xb + (size_t)(m0 + mrow) * K_ + w * 1152 + quad * 8;
      const unsigned short* bp = Bm + ((size_t)(w * 144 + quad) * C_ + c) * 128 + mrow * 8;
      if (t < 10) szed[t] = (it == 0) ? 1152.0f
                                      : atomicAdd(&Z[it * 10 + t], 0.0f);  // coherent
      f32x4 acc = {0.0f, 0.0f, 0.0f, 0.0f};
#pragma unroll 6
      for (int kk = 0; kk < 36; ++kk) {
        const bf16x8 a = *(const bf16x8*)(ap + kk * 32);
        const bf16x8 b = *(const bf16x8*)(bp + (size_t)kk * 5120);
        acc = __builtin_amdgcn_mfma_f32_16x16x32_bf16(a, b, acc, 0, 0, 0);
      }
#pragma unroll
      for (int rg = 0; rg < 4; ++rg)
        sred[w * 272 + mrow * 17 + quad * 4 + rg] = acc[rg];
      __syncthreads();
      if (t < 256) {
        int m, n;
        if (it == 2) { m = t >> 4; n = t & 15; } else { n = t >> 4; m = t & 15; }
        const int e = n * 17 + m;
        const float ss = ((sred[0 * 272 + e] + sred[1 * 272 + e]) +
                          (sred[2 * 272 + e] + sred[3 * 272 + e])) +
                         ((sred[4 * 272 + e] + sred[5 * 272 + e]) +
                          (sred[6 * 272 + e] + sred[7 * 272 + e]));
        const float s = ss / szed[c];
        const float v = s * fabsf(s) / (1.0f + s * s);   // squash
        if (it == 2) out[(size_t)(m0 + m) * SCO + c * 16 + n] = v;
        else {
          unsigned short* vbw = (it == 0) ? vb0 : vb1;   // ping-pong
          vbw[(size_t)(c * 16 + n) * 256 + m0 + m] = f2bf(v);
        }
      }
    }
    if (it == 2) break;
    gsync(bar, (unsigned)NB * (2 * it + 2));

    // ------------- pv: 72 blocks x 16 r, fused routing update --------------
    if (bx < 72) {
      unsigned short* svb = (unsigned short*)smem;       // 80 KB staged vb
      float* sp = (float*)smem;                          // alias: P tiles 80 KB
      float* sbs = (float*)(smem + 81920);               // 160 floats
      const unsigned short* vbr = (it == 0) ? vb0 : vb1;
      unsigned short* wb2w = (it == 0) ? wb2a : wb2b;
      const int seg = (bx & 7) * 9 + (bx >> 3);          // 0..71, XCD-swizzled
      const int r0 = seg * 16;
      const unsigned short* ap = xT + (size_t)(seg * 128 + w * 16 + mrow) * 256 + quad * 8;
      bf16x8 afr[8];
#pragma unroll
      for (int kk = 0; kk < 8; ++kk) afr[kk] = *(const bf16x8*)(ap + kk * 32);
      {  // stage vb -> LDS, XOR-swizzled (b128 reads conflict-reduced)
        const char* src = (const char*)vbr;
        char* dst = (char*)svb;
#pragma unroll
        for (int i = 0; i < 10; ++i) {
          const int ci = i * 512 + t;
          const int lin = ci * 16;
          const int n = ci >> 5;
          *(bf16x8*)(dst + (lin ^ ((n & 7) << 4))) = *(const bf16x8*)(src + lin);
        }
      }
      __syncthreads();
      f32x4 acc[10];
#pragma unroll
      for (int c = 0; c < 10; ++c) acc[c] = (f32x4){0.0f, 0.0f, 0.0f, 0.0f};
#pragma unroll
      for (int c = 0; c < 10; ++c) {
        const int n = c * 16 + mrow;
        const int base = n * 512 + quad * 16;
#pragma unroll
        for (int kk = 0; kk < 8; ++kk) {
          const bf16x8 b = *(const bf16x8*)((const char*)svb +
                            ((base + kk * 64) ^ ((n & 7) << 4)));
          acc[c] = __builtin_amdgcn_mfma_f32_16x16x32_bf16(afr[kk], b, acc[c], 0, 0, 0);
        }
      }
      __syncthreads();                       // svb reads done before sp overwrite
#pragma unroll
      for (int c = 0; c < 10; ++c)
#pragma unroll
        for (int rg = 0; rg < 4; ++rg) {
          const int ml = w * 16 + quad * 4 + rg;         // m = rl*8+i, 0..127
          sp[(c * 16 + (ml >> 3)) * 128 + mrow * 8 + (ml & 7)] = acc[c][rg];
        }
      __syncthreads();
      const int p16 = t >> 5, l32 = t & 31;
#pragma unroll
      for (int ch = 0; ch < 10; ++ch) {
        const int pair = ch * 16 + p16;                  // 0..159
        const int rl = pair / 10, c = pair - rl * 10;
        const float4 pv = *(const float4*)&sp[(c * 16 + rl) * 128 + l32 * 4];
        const float4 wv = *(const float4*)(W + (size_t)(r0 + rl) * 1280 + c * 128 + l32 * 4);
        float prod = wv.x * pv.x + wv.y * pv.y + wv.z * pv.z + wv.w * pv.w;
        prod += __shfl_xor(prod, 1);  prod += __shfl_xor(prod, 2);
        prod += __shfl_xor(prod, 4);  prod += __shfl_xor(prod, 8);
        prod += __shfl_xor(prod, 16);
        if (l32 == 0) sbs[rl * 10 + c] = prod;
      }
      __syncthreads();
      if (t < 160) {                                     // routing update + exp
        const int rl = t / 10, c = t - rl * 10;
        const int r = r0 + rl;
        float b = sbs[t] * (1.0f / 256.0f);
        if (it != 0) b += bvec[r * C_ + c];
        bvec[r * C_ + c] = b;
        sbs[t] = expf(b);                                // |b| << 1: safe
      }
      __syncthreads();
      if (t < 10) {
        float z = 0.0f;
#pragma unroll
        for (int rl = 0; rl < 16; ++rl) z += sbs[rl * 10 + t];
        atomicAdd(&Z[(it + 1) * 10 + t], z);
      }
      // regen wb2 slice = bf16(wraw * e): 16 r x 1280 = 20480 = 5 x 512 x 8
#pragma unroll
      for (int i = 0; i < 5; ++i) {
        const int base = i * 4096 + t * 8;
        const int rl = base / 1280, rem2 = base - rl * 1280;
        const int c = rem2 >> 7;
        const float e = sbs[rl * 10 + c];
        const size_t off = ((size_t)(r0 + rl) * C_ + c) * 128 + (rem2 & 127);
        const bf16x8 wv8 = *(const bf16x8*)(wraw + off);
        bf16x8 o8;
#pragma unroll
        for (int j = 0; j < 8; ++j)
          o8[j] = (short)f2bf(bf2f((unsigned short)wv8[j]) * e);
        *(bf16x8*)(wb2w + off) = o8;
      }
    }
    gsync(bar, (unsigned)NB * (2 * it + 3));
  }
}

extern "C" void kernel_launch(void* const* d_in, const int* in_sizes, int n_in,
                              void* d_out, int out_size, void* d_ws, size_t ws_size,
                              hipStream_t stream) {
  const float* x = (const float*)d_in[0];  // (B,R,I) fp32
  const float* W = (const float*)d_in[1];  // (R,C,O,I) fp32
  float* out = (float*)d_out;              // (B,C,O,1) fp32

  unsigned int* bar = (unsigned int*)d_ws;                 // 16 u32
  float* bvec = (float*)d_ws + 16;                         // 11520
  float* Z    = bvec + R_ * C_;                            // 32
  unsigned short* xb   = (unsigned short*)(Z + 32);        // B*K      = 2359296
  unsigned short* wraw = xb + (size_t)B_ * K_;             // R*C*O*I  = 1474560
  unsigned short* xT   = wraw + (size_t)R_ * C_ * O_ * I_; // R*8*256  = 2359296
  unsigned short* vb0  = xT + (size_t)R_ * 8 * 256;        // 160*256
  unsigned short* vb1  = vb0 + (size_t)160 * 256;
  unsigned short* wb2a = vb1 + (size_t)160 * 256;          // R*C*O*I
  unsigned short* wb2b = wb2a + (size_t)R_ * C_ * O_ * I_;

  hipMemsetAsync(bar, 0, 64, stream);                      // capture-safe
  mega<<<NB, 512, 0, stream>>>(x, W, out, bar, bvec, Z, xb, wraw, xT,
                               vb0, vb1, wb2a, wb2b);
}

// Round 5
// 217.329 us; speedup vs baseline: 1.2380x; 1.2380x over previous
//
#include <hip/hip_runtime.h>

static constexpr int B_ = 256;
static constexpr int R_ = 1152;
static constexpr int C_ = 10;
static constexpr int O_ = 16;
static constexpr int I_ = 8;
static constexpr int SCO = C_ * O_;   // 160
static constexpr int K_ = R_ * I_;    // 9216
static constexpr int NB = 256;        // grid = CU count, 1 block/CU via LDS

typedef short bf16x8 __attribute__((ext_vector_type(8)));
typedef float f32x4  __attribute__((ext_vector_type(4)));

__device__ __forceinline__ unsigned short f2bf(float f) {
  union { float f; unsigned int u; } c; c.f = f;
  const unsigned int u = c.u;
  return (unsigned short)((u + 0x7fffu + ((u >> 16) & 1u)) >> 16);  // RNE
}
__device__ __forceinline__ float bf2f(unsigned short h) {
  union { unsigned int u; float f; } c; c.u = ((unsigned int)h) << 16; return c.f;
}

// ---------------------------------------------------------------------------
// Low-contention grid barrier (r4 post-mortem: single-line spin congestion).
// Layout in bar[]: flags = bar[bx*16] (256 x 64B lines), go = bar[4096+x*16]
// (8 x 64B lines). Arrival: RELEASE store to own line (publishes this block's
// stores via wbL2, no RMW contention). Block 0: threads 0..255 poll distinct
// flag lines, then RELEASE-broadcast epoch to 8 go lines. Spinners poll
// go[bx&7] with ~0.85us backoff -> ~37 polls/us/line (was ~500 on ONE line).
// Acquire fence after: one L1/L2 invalidate per block (consume published data).
// Guards degrade to wrong-answer, never hang.
// ---------------------------------------------------------------------------
__device__ __forceinline__ void gsync(unsigned int* bar, unsigned int epoch) {
  __syncthreads();
  if (threadIdx.x == 0)
    __hip_atomic_store(&bar[blockIdx.x * 16], epoch,
                       __ATOMIC_RELEASE, __HIP_MEMORY_SCOPE_AGENT);
  if (blockIdx.x == 0) {
    if (threadIdx.x < 256) {
      int guard = 0;
      while (__hip_atomic_load(&bar[threadIdx.x * 16],
                               __ATOMIC_RELAXED, __HIP_MEMORY_SCOPE_AGENT) < epoch) {
        __builtin_amdgcn_s_sleep(8);            // ~512 cy between polls
        if (++guard > (1 << 17)) break;
      }
    }
    __syncthreads();
    if (threadIdx.x < 8)
      __hip_atomic_store(&bar[4096 + threadIdx.x * 16], epoch,
                         __ATOMIC_RELEASE, __HIP_MEMORY_SCOPE_AGENT);
  } else {
    if (threadIdx.x == 0) {
      unsigned int* g = &bar[4096 + (blockIdx.x & 7) * 16];
      int guard = 0;
      while (__hip_atomic_load(g, __ATOMIC_RELAXED,
                               __HIP_MEMORY_SCOPE_AGENT) < epoch) {
        __builtin_amdgcn_s_sleep(32);           // ~2048 cy between polls
        if (++guard > (1 << 16)) break;
      }
    }
  }
  __syncthreads();
  __builtin_amdgcn_fence(__ATOMIC_ACQUIRE, "agent");
}

// ===========================================================================
// mega: ONE plain launch, 256 blocks x 512 threads, 82.5 KB LDS (1 block/CU).
// Phase 0: [gemm0 (blocks 0..159, inline fp32->bf16 from x,W directly)
//           || prep (blocks 160..255: xb, wraw, xT for later phases)]
// then: pv(it0) -> gemm1 -> pv(it1) -> gemm2(final). 4 barriers total.
// All inter-phase buffers are write-once-per-address (vb/wb2 ping-pong).
// ===========================================================================
__global__ __launch_bounds__(512, 1) void mega(
    const float* __restrict__ x, const float* __restrict__ W,
    float* __restrict__ out, unsigned int* __restrict__ bar,
    float* __restrict__ bvec, float* __restrict__ Z,
    unsigned short* __restrict__ xb, unsigned short* __restrict__ wraw,
    unsigned short* __restrict__ xT,
    unsigned short* __restrict__ vb0, unsigned short* __restrict__ vb1,
    unsigned short* __restrict__ wb2a, unsigned short* __restrict__ wb2b) {
  __shared__ __align__(16) unsigned char smem[82560];
  const int bx = blockIdx.x;
  const int t = threadIdx.x;
  const int lane = t & 63;
  const int w = __builtin_amdgcn_readfirstlane(t >> 6);   // 0..7
  const int mrow = lane & 15, quad = lane >> 4;

  if (bx == 0 && t < 32) Z[t] = 0.0f;          // Z[10..29] accumulated by pv

  // ======================= Phase 0: gemm0 || prep ==========================
  if (bx < 160) {
    // gemm0: B = bf16(W), A = bf16(x), both converted inline (bit-identical
    // to the xb/wraw path: same f2bf RNE). 1/1152 folded into epilogue.
    float* sred = (float*)smem;                // 8 x 272 floats
    const int g = (bx & 7) * 20 + (bx >> 3);   // XCD: 2 mtiles x 10 c
    const int mtile = g / 10, c = g - mtile * 10;
    const int m0 = mtile * 16;
    const float* apf = x + (size_t)(m0 + mrow) * K_ + w * 1152 + quad * 8;
    const float* bpf = W + ((size_t)(w * 144 + quad) * C_ + c) * 128 + mrow * 8;
    f32x4 acc = {0.0f, 0.0f, 0.0f, 0.0f};
#pragma unroll 4
    for (int kk = 0; kk < 36; ++kk) {
      const float4 a0 = *(const float4*)(apf + kk * 32);
      const float4 a1 = *(const float4*)(apf + kk * 32 + 4);
      const float4 b0 = *(const float4*)(bpf + (size_t)kk * 5120);
      const float4 b1 = *(const float4*)(bpf + (size_t)kk * 5120 + 4);
      bf16x8 a, b;
      a[0] = (short)f2bf(a0.x); a[1] = (short)f2bf(a0.y);
      a[2] = (short)f2bf(a0.z); a[3] = (short)f2bf(a0.w);
      a[4] = (short)f2bf(a1.x); a[5] = (short)f2bf(a1.y);
      a[6] = (short)f2bf(a1.z); a[7] = (short)f2bf(a1.w);
      b[0] = (short)f2bf(b0.x); b[1] = (short)f2bf(b0.y);
      b[2] = (short)f2bf(b0.z); b[3] = (short)f2bf(b0.w);
      b[4] = (short)f2bf(b1.x); b[5] = (short)f2bf(b1.y);
      b[6] = (short)f2bf(b1.z); b[7] = (short)f2bf(b1.w);
      acc = __builtin_amdgcn_mfma_f32_16x16x32_bf16(a, b, acc, 0, 0, 0);
    }
#pragma unroll
    for (int rg = 0; rg < 4; ++rg)
      sred[w * 272 + mrow * 17 + quad * 4 + rg] = acc[rg];
    __syncthreads();
    if (t < 256) {
      const int n = t >> 4, m = t & 15;        // vb layout write
      const int e = n * 17 + m;
      const float ss = ((sred[0 * 272 + e] + sred[1 * 272 + e]) +
                        (sred[2 * 272 + e] + sred[3 * 272 + e])) +
                       ((sred[4 * 272 + e] + sred[5 * 272 + e]) +
                        (sred[6 * 272 + e] + sred[7 * 272 + e]));
      const float s = ss * (1.0f / 1152.0f);
      const float v = s * fabsf(s) / (1.0f + s * s);     // squash
      vb0[(size_t)(c * 16 + n) * 256 + m0 + m] = f2bf(v);
    }
  } else {
    // prep on 96 blocks: W -> wraw (3840 float4 each, exact), x -> xb + xT.
    const float4* wf = (const float4*)W;
    ushort4* wr = (ushort4*)wraw;
    for (int idx = t; idx < 3840; idx += 512) {
      const int j = (bx - 160) * 3840 + idx;
      const float4 v4 = wf[j];
      ushort4 r4;
      r4.x = f2bf(v4.x); r4.y = f2bf(v4.y); r4.z = f2bf(v4.z); r4.w = f2bf(v4.w);
      wr[j] = r4;
    }
    float* sx = (float*)smem;                  // 144 x 68 floats = 39168 B
    for (int u = bx - 160; u < 256; u += 96) { // 2-3 units of (64 b x 18 r)
      const int bq = u & 3, rseg = u >> 2;
      const int rbase = rseg * 18;
      __syncthreads();                         // sx reuse guard
      for (int idx = t; idx < 64 * 36; idx += 512) {
        const int b = idx / 36, f4 = idx - b * 36;
        const size_t off = (size_t)(bq * 64 + b) * K_ + rbase * I_ + f4 * 4;
        const float4 val = *(const float4*)(x + off);
        ushort4 o4;
        o4.x = f2bf(val.x); o4.y = f2bf(val.y); o4.z = f2bf(val.z); o4.w = f2bf(val.w);
        *(ushort4*)(xb + off) = o4;
        const int rr = f4 >> 1, i4 = (f4 & 1) * 4;
        sx[(rr * 8 + i4 + 0) * 68 + b] = val.x;
        sx[(rr * 8 + i4 + 1) * 68 + b] = val.y;
        sx[(rr * 8 + i4 + 2) * 68 + b] = val.z;
        sx[(rr * 8 + i4 + 3) * 68 + b] = val.w;
      }
      __syncthreads();
      for (int row = w * 18; row < w * 18 + 18; ++row)
        xT[(size_t)(rseg * 144 + row) * 256 + bq * 64 + lane] = f2bf(sx[row * 68 + lane]);
    }
  }
  gsync(bar, 1);

  for (int it = 0; it < 2; ++it) {
    // ------------- pv: 72 blocks x 16 r, fused routing update --------------
    if (bx < 72) {
      unsigned short* svb = (unsigned short*)smem;       // 80 KB staged vb
      float* sp = (float*)smem;                          // alias: P tiles
      float* sbs = (float*)(smem + 81920);               // 160 floats
      const unsigned short* vbr = (it == 0) ? vb0 : vb1;
      unsigned short* wb2w = (it == 0) ? wb2a : wb2b;
      const int seg = (bx & 7) * 9 + (bx >> 3);          // 0..71, XCD-swizzled
      const int r0 = seg * 16;
      const unsigned short* ap = xT + (size_t)(seg * 128 + w * 16 + mrow) * 256 + quad * 8;
      bf16x8 afr[8];
#pragma unroll
      for (int kk = 0; kk < 8; ++kk) afr[kk] = *(const bf16x8*)(ap + kk * 32);
      {  // stage vb -> LDS, XOR-swizzled
        const char* src = (const char*)vbr;
        char* dst = (char*)svb;
#pragma unroll
        for (int i = 0; i < 10; ++i) {
          const int ci = i * 512 + t;
          const int lin = ci * 16;
          const int n = ci >> 5;
          *(bf16x8*)(dst + (lin ^ ((n & 7) << 4))) = *(const bf16x8*)(src + lin);
        }
      }
      __syncthreads();
      f32x4 acc[10];
#pragma unroll
      for (int c = 0; c < 10; ++c) acc[c] = (f32x4){0.0f, 0.0f, 0.0f, 0.0f};
#pragma unroll
      for (int c = 0; c < 10; ++c) {
        const int n = c * 16 + mrow;
        const int base = n * 512 + quad * 16;
#pragma unroll
        for (int kk = 0; kk < 8; ++kk) {
          const bf16x8 b = *(const bf16x8*)((const char*)svb +
                            ((base + kk * 64) ^ ((n & 7) << 4)));
          acc[c] = __builtin_amdgcn_mfma_f32_16x16x32_bf16(afr[kk], b, acc[c], 0, 0, 0);
        }
      }
      __syncthreads();                         // svb reads done before overwrite
#pragma unroll
      for (int c = 0; c < 10; ++c)
#pragma unroll
        for (int rg = 0; rg < 4; ++rg) {
          const int ml = w * 16 + quad * 4 + rg;         // m = rl*8+i
          sp[(c * 16 + (ml >> 3)) * 128 + mrow * 8 + (ml & 7)] = acc[c][rg];
        }
      __syncthreads();
      const int p16 = t >> 5, l32 = t & 31;
#pragma unroll
      for (int ch = 0; ch < 10; ++ch) {
        const int pair = ch * 16 + p16;                  // 0..159
        const int rl = pair / 10, c = pair - rl * 10;
        const float4 pv = *(const float4*)&sp[(c * 16 + rl) * 128 + l32 * 4];
        const float4 wv = *(const float4*)(W + (size_t)(r0 + rl) * 1280 + c * 128 + l32 * 4);
        float prod = wv.x * pv.x + wv.y * pv.y + wv.z * pv.z + wv.w * pv.w;
        prod += __shfl_xor(prod, 1);  prod += __shfl_xor(prod, 2);
        prod += __shfl_xor(prod, 4);  prod += __shfl_xor(prod, 8);
        prod += __shfl_xor(prod, 16);
        if (l32 == 0) sbs[rl * 10 + c] = prod;
      }
      __syncthreads();
      if (t < 160) {                                     // routing update + exp
        const int rl = t / 10, c = t - rl * 10;
        const int r = r0 + rl;
        float b = sbs[t] * (1.0f / 256.0f);
        if (it != 0) b += bvec[r * C_ + c];
        bvec[r * C_ + c] = b;
        sbs[t] = expf(b);                                // |b| << 1: safe
      }
      __syncthreads();
      if (t < 10) {
        float z = 0.0f;
#pragma unroll
        for (int rl = 0; rl < 16; ++rl) z += sbs[rl * 10 + t];
        atomicAdd(&Z[(it + 1) * 10 + t], z);
      }
      // regen wb2 slice = bf16(wraw * e)
#pragma unroll
      for (int i = 0; i < 5; ++i) {
        const int base = i * 4096 + t * 8;
        const int rl = base / 1280, rem2 = base - rl * 1280;
        const int c = rem2 >> 7;
        const float e = sbs[rl * 10 + c];
        const size_t off = ((size_t)(r0 + rl) * C_ + c) * 128 + (rem2 & 127);
        const bf16x8 wv8 = *(const bf16x8*)(wraw + off);
        bf16x8 o8;
#pragma unroll
        for (int j = 0; j < 8; ++j)
          o8[j] = (short)f2bf(bf2f((unsigned short)wv8[j]) * e);
        *(bf16x8*)(wb2w + off) = o8;
      }
    }
    gsync(bar, 2 + 2 * it);

    // ------------- gemm (it+1): 160 blocks, full-K, bf16 inputs ------------
    {
      const int git = it + 1;                  // 1 or 2
      if (bx < 160) {
        float* sred = (float*)smem;
        float* szed = (float*)(smem + 16384);
        const unsigned short* Bm = (git == 1) ? wb2a : wb2b;
        const int g = (bx & 7) * 20 + (bx >> 3);
        const int mtile = g / 10, c = g - mtile * 10;
        const int m0 = mtile * 16;
        const unsigned short* ap = xb + (size_t)(m0 + mrow) * K_ + w * 1152 + quad * 8;
        const unsigned short* bp = Bm + ((size_t)(w * 144 + quad) * C_ + c) * 128 + mrow * 8;
        if (t < 10) szed[t] = atomicAdd(&Z[git * 10 + t], 0.0f);  // coherent read
        f32x4 acc = {0.0f, 0.0f, 0.0f, 0.0f};
#pragma unroll 6
        for (int kk = 0; kk < 36; ++kk) {
          const bf16x8 a = *(const bf16x8*)(ap + kk * 32);
          const bf16x8 b = *(const bf16x8*)(bp + (size_t)kk * 5120);
          acc = __builtin_amdgcn_mfma_f32_16x16x32_bf16(a, b, acc, 0, 0, 0);
        }
#pragma unroll
        for (int rg = 0; rg < 4; ++rg)
          sred[w * 272 + mrow * 17 + quad * 4 + rg] = acc[rg];
        __syncthreads();
        if (t < 256) {
          int m, n;
          if (git == 2) { m = t >> 4; n = t & 15; } else { n = t >> 4; m = t & 15; }
          const int e = n * 17 + m;
          const float ss = ((sred[0 * 272 + e] + sred[1 * 272 + e]) +
                            (sred[2 * 272 + e] + sred[3 * 272 + e])) +
                           ((sred[4 * 272 + e] + sred[5 * 272 + e]) +
                            (sred[6 * 272 + e] + sred[7 * 272 + e]));
          const float s = ss / szed[c];
          const float v = s * fabsf(s) / (1.0f + s * s); // squash
          if (git == 2) out[(size_t)(m0 + m) * SCO + c * 16 + n] = v;
          else          vb1[(size_t)(c * 16 + n) * 256 + m0 + m] = f2bf(v);
        }
      }
    }
    if (it == 0) gsync(bar, 3);
  }
}

extern "C" void kernel_launch(void* const* d_in, const int* in_sizes, int n_in,
                              void* d_out, int out_size, void* d_ws, size_t ws_size,
                              hipStream_t stream) {
  const float* x = (const float*)d_in[0];  // (B,R,I) fp32
  const float* W = (const float*)d_in[1];  // (R,C,O,I) fp32
  float* out = (float*)d_out;              // (B,C,O,1) fp32

  unsigned int* bar = (unsigned int*)d_ws;                 // 4224 u32 = 16896 B
  float* bvec = (float*)d_ws + 4224;                       // 11520
  float* Z    = bvec + R_ * C_;                            // 32
  unsigned short* xb   = (unsigned short*)(Z + 32);        // B*K
  unsigned short* wraw = xb + (size_t)B_ * K_;             // R*C*O*I
  unsigned short* xT   = wraw + (size_t)R_ * C_ * O_ * I_; // R*8*256
  unsigned short* vb0  = xT + (size_t)R_ * 8 * 256;        // 160*256
  unsigned short* vb1  = vb0 + (size_t)160 * 256;
  unsigned short* wb2a = vb1 + (size_t)160 * 256;          // R*C*O*I
  unsigned short* wb2b = wb2a + (size_t)R_ * C_ * O_ * I_;

  hipMemsetAsync(bar, 0, 16896, stream);                   // capture-safe
  mega<<<NB, 512, 0, stream>>>(x, W, out, bar, bvec, Z, xb, wraw, xT,
                               vb0, vb1, wb2a, wb2b);
}

// Round 7
// 161.460 us; speedup vs baseline: 1.6663x; 1.3460x over previous
//
#include <hip/hip_runtime.h>

static constexpr int B_ = 256;
static constexpr int R_ = 1152;
static constexpr int C_ = 10;
static constexpr int O_ = 16;
static constexpr int I_ = 8;
static constexpr int SCO = C_ * O_;   // 160
static constexpr int K_ = R_ * I_;    // 9216
static constexpr int NB = 256;        // grid = CU count, 1 block/CU via LDS

typedef short bf16x8 __attribute__((ext_vector_type(8)));
typedef float f32x4  __attribute__((ext_vector_type(4)));

__device__ __forceinline__ unsigned short f2bf(float f) {
  union { float f; unsigned int u; } c; c.f = f;
  const unsigned int u = c.u;
  return (unsigned short)((u + 0x7fffu + ((u >> 16) & 1u)) >> 16);  // RNE
}
__device__ __forceinline__ float bf2f(unsigned short h) {
  union { unsigned int u; float f; } c; c.u = ((unsigned int)h) << 16; return c.f;
}

// ---------------------------------------------------------------------------
// Low-contention grid barrier, NO hardware acquire (r5 post-mortem).
// r5's fence(ACQUIRE,"agent") emitted buffer_inv (L1+L2) 5x/launch -> every
// phase re-streamed its working set from L3 at 1 block/CU (measured: 74.5 MB
// FETCH, 600 GB/s effective, 161 us body). The invalidate is UNNECESSARY here:
// all inter-phase buffers are write-once-per-address per launch (vb/wb2
// ping-pong; xb/wraw/xT phase-0 only), and each address is first read only
// after the producer's RELEASE store (whose wbL2 pushes the data to L3). A
// consumer L2 can only be stale for lines it cached earlier in the launch --
// which write-once precludes (kernel entry starts invalidated). So hardware
// needs nothing; only the compiler must not hoist loads above the spin ->
// empty asm with memory clobber. Z uses device-scope atomics (always coherent).
// Arrival: RELEASE store to own 64B flag line (no RMW contention). Block 0:
// threads 0..255 poll distinct flag lines, then RELEASE-broadcast to 8 go
// lines (release orders the flag-reads before the go-store -> transitivity).
// Guards degrade to wrong-answer, never hang.
// ---------------------------------------------------------------------------
__device__ __forceinline__ void gsync(unsigned int* bar, unsigned int epoch) {
  __syncthreads();
  if (threadIdx.x == 0)
    __hip_atomic_store(&bar[blockIdx.x * 16], epoch,
                       __ATOMIC_RELEASE, __HIP_MEMORY_SCOPE_AGENT);
  if (blockIdx.x == 0) {
    if (threadIdx.x < 256) {
      int guard = 0;
      while (__hip_atomic_load(&bar[threadIdx.x * 16],
                               __ATOMIC_RELAXED, __HIP_MEMORY_SCOPE_AGENT) < epoch) {
        __builtin_amdgcn_s_sleep(8);            // ~512 cy between polls
        if (++guard > (1 << 17)) break;
      }
    }
    __syncthreads();
    if (threadIdx.x < 8)
      __hip_atomic_store(&bar[4096 + threadIdx.x * 16], epoch,
                         __ATOMIC_RELEASE, __HIP_MEMORY_SCOPE_AGENT);
  } else {
    if (threadIdx.x == 0) {
      unsigned int* g = &bar[4096 + (blockIdx.x & 7) * 16];
      int guard = 0;
      while (__hip_atomic_load(g, __ATOMIC_RELAXED,
                               __HIP_MEMORY_SCOPE_AGENT) < epoch) {
        __builtin_amdgcn_s_sleep(32);           // ~2048 cy between polls
        if (++guard > (1 << 16)) break;
      }
    }
  }
  __syncthreads();
  asm volatile("" ::: "memory");   // compiler barrier ONLY -- no buffer_inv
}

// ===========================================================================
// mega: ONE plain launch, 256 blocks x 512 threads, 82.5 KB LDS (1 block/CU).
// Phase 0: [gemm0 (blocks 0..159, inline fp32->bf16 from x,W directly)
//           || prep (blocks 160..255: xb, wraw, xT for later phases)]
// then: pv(it0) -> gemm1 -> pv(it1) -> gemm2(final). 4 barriers total.
// All inter-phase buffers are write-once-per-address (vb/wb2 ping-pong).
// ===========================================================================
__global__ __launch_bounds__(512, 1) void mega(
    const float* __restrict__ x, const float* __restrict__ W,
    float* __restrict__ out, unsigned int* __restrict__ bar,
    float* __restrict__ bvec, float* __restrict__ Z,
    unsigned short* __restrict__ xb, unsigned short* __restrict__ wraw,
    unsigned short* __restrict__ xT,
    unsigned short* __restrict__ vb0, unsigned short* __restrict__ vb1,
    unsigned short* __restrict__ wb2a, unsigned short* __restrict__ wb2b) {
  __shared__ __align__(16) unsigned char smem[82560];
  const int bx = blockIdx.x;
  const int t = threadIdx.x;
  const int lane = t & 63;
  const int w = __builtin_amdgcn_readfirstlane(t >> 6);   // 0..7
  const int mrow = lane & 15, quad = lane >> 4;

  if (bx == 0 && t < 32) Z[t] = 0.0f;          // Z[10..29] accumulated by pv

  // ======================= Phase 0: gemm0 || prep ==========================
  if (bx < 160) {
    // gemm0: B = bf16(W), A = bf16(x), both converted inline (bit-identical
    // to the xb/wraw path: same f2bf RNE). 1/1152 folded into epilogue.
    float* sred = (float*)smem;                // 8 x 272 floats
    const int g = (bx & 7) * 20 + (bx >> 3);   // XCD: 2 mtiles x 10 c
    const int mtile = g / 10, c = g - mtile * 10;
    const int m0 = mtile * 16;
    const float* apf = x + (size_t)(m0 + mrow) * K_ + w * 1152 + quad * 8;
    const float* bpf = W + ((size_t)(w * 144 + quad) * C_ + c) * 128 + mrow * 8;
    f32x4 acc = {0.0f, 0.0f, 0.0f, 0.0f};
#pragma unroll 4
    for (int kk = 0; kk < 36; ++kk) {
      const float4 a0 = *(const float4*)(apf + kk * 32);
      const float4 a1 = *(const float4*)(apf + kk * 32 + 4);
      const float4 b0 = *(const float4*)(bpf + (size_t)kk * 5120);
      const float4 b1 = *(const float4*)(bpf + (size_t)kk * 5120 + 4);
      bf16x8 a, b;
      a[0] = (short)f2bf(a0.x); a[1] = (short)f2bf(a0.y);
      a[2] = (short)f2bf(a0.z); a[3] = (short)f2bf(a0.w);
      a[4] = (short)f2bf(a1.x); a[5] = (short)f2bf(a1.y);
      a[6] = (short)f2bf(a1.z); a[7] = (short)f2bf(a1.w);
      b[0] = (short)f2bf(b0.x); b[1] = (short)f2bf(b0.y);
      b[2] = (short)f2bf(b0.z); b[3] = (short)f2bf(b0.w);
      b[4] = (short)f2bf(b1.x); b[5] = (short)f2bf(b1.y);
      b[6] = (short)f2bf(b1.z); b[7] = (short)f2bf(b1.w);
      acc = __builtin_amdgcn_mfma_f32_16x16x32_bf16(a, b, acc, 0, 0, 0);
    }
#pragma unroll
    for (int rg = 0; rg < 4; ++rg)
      sred[w * 272 + mrow * 17 + quad * 4 + rg] = acc[rg];
    __syncthreads();
    if (t < 256) {
      const int n = t >> 4, m = t & 15;        // vb layout write
      const int e = n * 17 + m;
      const float ss = ((sred[0 * 272 + e] + sred[1 * 272 + e]) +
                        (sred[2 * 272 + e] + sred[3 * 272 + e])) +
                       ((sred[4 * 272 + e] + sred[5 * 272 + e]) +
                        (sred[6 * 272 + e] + sred[7 * 272 + e]));
      const float s = ss * (1.0f / 1152.0f);
      const float v = s * fabsf(s) / (1.0f + s * s);     // squash
      vb0[(size_t)(c * 16 + n) * 256 + m0 + m] = f2bf(v);
    }
  } else {
    // prep on 96 blocks: W -> wraw (3840 float4 each, exact), x -> xb + xT.
    const float4* wf = (const float4*)W;
    ushort4* wr = (ushort4*)wraw;
    for (int idx = t; idx < 3840; idx += 512) {
      const int j = (bx - 160) * 3840 + idx;
      const float4 v4 = wf[j];
      ushort4 r4;
      r4.x = f2bf(v4.x); r4.y = f2bf(v4.y); r4.z = f2bf(v4.z); r4.w = f2bf(v4.w);
      wr[j] = r4;
    }
    float* sx = (float*)smem;                  // 144 x 68 floats = 39168 B
    for (int u = bx - 160; u < 256; u += 96) { // 2-3 units of (64 b x 18 r)
      const int bq = u & 3, rseg = u >> 2;
      const int rbase = rseg * 18;
      __syncthreads();                         // sx reuse guard
      for (int idx = t; idx < 64 * 36; idx += 512) {
        const int b = idx / 36, f4 = idx - b * 36;
        const size_t off = (size_t)(bq * 64 + b) * K_ + rbase * I_ + f4 * 4;
        const float4 val = *(const float4*)(x + off);
        ushort4 o4;
        o4.x = f2bf(val.x); o4.y = f2bf(val.y); o4.z = f2bf(val.z); o4.w = f2bf(val.w);
        *(ushort4*)(xb + off) = o4;
        const int rr = f4 >> 1, i4 = (f4 & 1) * 4;
        sx[(rr * 8 + i4 + 0) * 68 + b] = val.x;
        sx[(rr * 8 + i4 + 1) * 68 + b] = val.y;
        sx[(rr * 8 + i4 + 2) * 68 + b] = val.z;
        sx[(rr * 8 + i4 + 3) * 68 + b] = val.w;
      }
      __syncthreads();
      for (int row = w * 18; row < w * 18 + 18; ++row)
        xT[(size_t)(rseg * 144 + row) * 256 + bq * 64 + lane] = f2bf(sx[row * 68 + lane]);
    }
  }
  gsync(bar, 1);

  for (int it = 0; it < 2; ++it) {
    // ------------- pv: 72 blocks x 16 r, fused routing update --------------
    if (bx < 72) {
      unsigned short* svb = (unsigned short*)smem;       // 80 KB staged vb
      float* sp = (float*)smem;                          // alias: P tiles
      float* sbs = (float*)(smem + 81920);               // 160 floats
      const unsigned short* vbr = (it == 0) ? vb0 : vb1;
      unsigned short* wb2w = (it == 0) ? wb2a : wb2b;
      const int seg = (bx & 7) * 9 + (bx >> 3);          // 0..71, XCD-swizzled
      const int r0 = seg * 16;
      const unsigned short* ap = xT + (size_t)(seg * 128 + w * 16 + mrow) * 256 + quad * 8;
      bf16x8 afr[8];
#pragma unroll
      for (int kk = 0; kk < 8; ++kk) afr[kk] = *(const bf16x8*)(ap + kk * 32);
      {  // stage vb -> LDS, XOR-swizzled
        const char* src = (const char*)vbr;
        char* dst = (char*)svb;
#pragma unroll
        for (int i = 0; i < 10; ++i) {
          const int ci = i * 512 + t;
          const int lin = ci * 16;
          const int n = ci >> 5;
          *(bf16x8*)(dst + (lin ^ ((n & 7) << 4))) = *(const bf16x8*)(src + lin);
        }
      }
      __syncthreads();
      f32x4 acc[10];
#pragma unroll
      for (int c = 0; c < 10; ++c) acc[c] = (f32x4){0.0f, 0.0f, 0.0f, 0.0f};
#pragma unroll
      for (int c = 0; c < 10; ++c) {
        const int n = c * 16 + mrow;
        const int base = n * 512 + quad * 16;
#pragma unroll
        for (int kk = 0; kk < 8; ++kk) {
          const bf16x8 b = *(const bf16x8*)((const char*)svb +
                            ((base + kk * 64) ^ ((n & 7) << 4)));
          acc[c] = __builtin_amdgcn_mfma_f32_16x16x32_bf16(afr[kk], b, acc[c], 0, 0, 0);
        }
      }
      __syncthreads();                         // svb reads done before overwrite
#pragma unroll
      for (int c = 0; c < 10; ++c)
#pragma unroll
        for (int rg = 0; rg < 4; ++rg) {
          const int ml = w * 16 + quad * 4 + rg;         // m = rl*8+i
          sp[(c * 16 + (ml >> 3)) * 128 + mrow * 8 + (ml & 7)] = acc[c][rg];
        }
      __syncthreads();
      const int p16 = t >> 5, l32 = t & 31;
#pragma unroll
      for (int ch = 0; ch < 10; ++ch) {
        const int pair = ch * 16 + p16;                  // 0..159
        const int rl = pair / 10, c = pair - rl * 10;
        const float4 pv = *(const float4*)&sp[(c * 16 + rl) * 128 + l32 * 4];
        const float4 wv = *(const float4*)(W + (size_t)(r0 + rl) * 1280 + c * 128 + l32 * 4);
        float prod = wv.x * pv.x + wv.y * pv.y + wv.z * pv.z + wv.w * pv.w;
        prod += __shfl_xor(prod, 1);  prod += __shfl_xor(prod, 2);
        prod += __shfl_xor(prod, 4);  prod += __shfl_xor(prod, 8);
        prod += __shfl_xor(prod, 16);
        if (l32 == 0) sbs[rl * 10 + c] = prod;
      }
      __syncthreads();
      if (t < 160) {                                     // routing update + exp
        const int rl = t / 10, c = t - rl * 10;
        const int r = r0 + rl;
        float b = sbs[t] * (1.0f / 256.0f);
        if (it != 0) b += bvec[r * C_ + c];
        bvec[r * C_ + c] = b;
        sbs[t] = expf(b);                                // |b| << 1: safe
      }
      __syncthreads();
      if (t < 10) {
        float z = 0.0f;
#pragma unroll
        for (int rl = 0; rl < 16; ++rl) z += sbs[rl * 10 + t];
        atomicAdd(&Z[(it + 1) * 10 + t], z);
      }
      // regen wb2 slice = bf16(wraw * e)
#pragma unroll
      for (int i = 0; i < 5; ++i) {
        const int base = i * 4096 + t * 8;
        const int rl = base / 1280, rem2 = base - rl * 1280;
        const int c = rem2 >> 7;
        const float e = sbs[rl * 10 + c];
        const size_t off = ((size_t)(r0 + rl) * C_ + c) * 128 + (rem2 & 127);
        const bf16x8 wv8 = *(const bf16x8*)(wraw + off);
        bf16x8 o8;
#pragma unroll
        for (int j = 0; j < 8; ++j)
          o8[j] = (short)f2bf(bf2f((unsigned short)wv8[j]) * e);
        *(bf16x8*)(wb2w + off) = o8;
      }
    }
    gsync(bar, 2 + 2 * it);

    // ------------- gemm (it+1): 160 blocks, full-K, bf16 inputs ------------
    {
      const int git = it + 1;                  // 1 or 2
      if (bx < 160) {
        float* sred = (float*)smem;
        float* szed = (float*)(smem + 16384);
        const unsigned short* Bm = (git == 1) ? wb2a : wb2b;
        const int g = (bx & 7) * 20 + (bx >> 3);
        const int mtile = g / 10, c = g - mtile * 10;
        const int m0 = mtile * 16;
        const unsigned short* ap = xb + (size_t)(m0 + mrow) * K_ + w * 1152 + quad * 8;
        const unsigned short* bp = Bm + ((size_t)(w * 144 + quad) * C_ + c) * 128 + mrow * 8;
        if (t < 10) szed[t] = atomicAdd(&Z[git * 10 + t], 0.0f);  // coherent read
        f32x4 acc = {0.0f, 0.0f, 0.0f, 0.0f};
#pragma unroll 6
        for (int kk = 0; kk < 36; ++kk) {
          const bf16x8 a = *(const bf16x8*)(ap + kk * 32);
          const bf16x8 b = *(const bf16x8*)(bp + (size_t)kk * 5120);
          acc = __builtin_amdgcn_mfma_f32_16x16x32_bf16(a, b, acc, 0, 0, 0);
        }
#pragma unroll
        for (int rg = 0; rg < 4; ++rg)
          sred[w * 272 + mrow * 17 + quad * 4 + rg] = acc[rg];
        __syncthreads();
        if (t < 256) {
          int m, n;
          if (git == 2) { m = t >> 4; n = t & 15; } else { n = t >> 4; m = t & 15; }
          const int e = n * 17 + m;
          const float ss = ((sred[0 * 272 + e] + sred[1 * 272 + e]) +
                            (sred[2 * 272 + e] + sred[3 * 272 + e])) +
                           ((sred[4 * 272 + e] + sred[5 * 272 + e]) +
                            (sred[6 * 272 + e] + sred[7 * 272 + e]));
          const float s = ss / szed[c];
          const float v = s * fabsf(s) / (1.0f + s * s); // squash
          if (git == 2) out[(size_t)(m0 + m) * SCO + c * 16 + n] = v;
          else          vb1[(size_t)(c * 16 + n) * 256 + m0 + m] = f2bf(v);
        }
      }
    }
    if (it == 0) gsync(bar, 3);
  }
}

extern "C" void kernel_launch(void* const* d_in, const int* in_sizes, int n_in,
                              void* d_out, int out_size, void* d_ws, size_t ws_size,
                              hipStream_t stream) {
  const float* x = (const float*)d_in[0];  // (B,R,I) fp32
  const float* W = (const float*)d_in[1];  // (R,C,O,I) fp32
  float* out = (float*)d_out;              // (B,C,O,1) fp32

  unsigned int* bar = (unsigned int*)d_ws;                 // 4224 u32 = 16896 B
  float* bvec = (float*)d_ws + 4224;                       // 11520
  float* Z    = bvec + R_ * C_;                            // 32
  unsigned short* xb   = (unsigned short*)(Z + 32);        // B*K
  unsigned short* wraw = xb + (size_t)B_ * K_;             // R*C*O*I
  unsigned short* xT   = wraw + (size_t)R_ * C_ * O_ * I_; // R*8*256
  unsigned short* vb0  = xT + (size_t)R_ * 8 * 256;        // 160*256
  unsigned short* vb1  = vb0 + (size_t)160 * 256;
  unsigned short* wb2a = vb1 + (size_t)160 * 256;          // R*C*O*I
  unsigned short* wb2b = wb2a + (size_t)R_ * C_ * O_ * I_;

  hipMemsetAsync(bar, 0, 16896, stream);                   // capture-safe
  mega<<<NB, 512, 0, stream>>>(x, W, out, bar, bvec, Z, xb, wraw, xT,
                               vb0, vb1, wb2a, wb2b);
}

// Round 8
// 150.517 us; speedup vs baseline: 1.7875x; 1.0727x over previous
//
#include <hip/hip_runtime.h>

static constexpr int B_ = 256;
static constexpr int R_ = 1152;
static constexpr int C_ = 10;
static constexpr int O_ = 16;
static constexpr int I_ = 8;
static constexpr int SCO = C_ * O_;   // 160
static constexpr int K_ = R_ * I_;    // 9216
static constexpr int NB = 256;        // grid = CU count, 1 block/CU via LDS

typedef short bf16x8 __attribute__((ext_vector_type(8)));
typedef float f32x4  __attribute__((ext_vector_type(4)));

__device__ __forceinline__ unsigned short f2bf(float f) {
  union { float f; unsigned int u; } c; c.f = f;
  const unsigned int u = c.u;
  return (unsigned short)((u + 0x7fffu + ((u >> 16) & 1u)) >> 16);  // RNE
}
__device__ __forceinline__ float bf2f(unsigned short h) {
  union { unsigned int u; float f; } c; c.u = ((unsigned int)h) << 16; return c.f;
}

// ---------------------------------------------------------------------------
// Low-contention grid barrier, compiler-fence only (validated r7: body 161->104
// us vs r5's per-barrier L2 invalidate; FETCH unchanged -> invalidate cost was
// stall, not refetch). Safety: all inter-phase buffers write-once-per-address
// per launch; consumers first touch an address only after the producer's
// RELEASE (wbL2) -> no stale L2 line can exist (kernel entry is invalidated).
// Z uses device-scope atomics. Guards degrade to wrong-answer, never hang.
// ---------------------------------------------------------------------------
__device__ __forceinline__ void gsync(unsigned int* bar, unsigned int epoch) {
  __syncthreads();
  if (threadIdx.x == 0)
    __hip_atomic_store(&bar[blockIdx.x * 16], epoch,
                       __ATOMIC_RELEASE, __HIP_MEMORY_SCOPE_AGENT);
  if (blockIdx.x == 0) {
    if (threadIdx.x < 256) {
      int guard = 0;
      while (__hip_atomic_load(&bar[threadIdx.x * 16],
                               __ATOMIC_RELAXED, __HIP_MEMORY_SCOPE_AGENT) < epoch) {
        __builtin_amdgcn_s_sleep(8);
        if (++guard > (1 << 17)) break;
      }
    }
    __syncthreads();
    if (threadIdx.x < 8)
      __hip_atomic_store(&bar[4096 + threadIdx.x * 16], epoch,
                         __ATOMIC_RELEASE, __HIP_MEMORY_SCOPE_AGENT);
  } else {
    if (threadIdx.x == 0) {
      unsigned int* g = &bar[4096 + (blockIdx.x & 7) * 16];
      int guard = 0;
      while (__hip_atomic_load(g, __ATOMIC_RELAXED,
                               __HIP_MEMORY_SCOPE_AGENT) < epoch) {
        __builtin_amdgcn_s_sleep(32);
        if (++guard > (1 << 16)) break;
      }
    }
  }
  __syncthreads();
  asm volatile("" ::: "memory");   // compiler barrier only
}

// ---------------------------------------------------------------------------
// gemm phase: 160 blocks, (4,5) XCD tiling (xcd-pair owns 4 mtiles, xcd owns
// 5 c -> 2.66 MB/XCD unique; L2-resident across all three passes). B operand
// is ALWAYS wraw; for git>0 it is scaled inline by e[c][r] (bit-identical to
// the old materialized wb2 = f2bf(bf2f(wraw)*e) path). Softmax denominator
// Z[git] read via device-scope atomic; epilogue squash -> vb (bf16, [co][b])
// or out (fp32).
// ---------------------------------------------------------------------------
__device__ __forceinline__ void gemm_phase(
    int git, const unsigned short* __restrict__ xb,
    const unsigned short* __restrict__ wraw, const float* __restrict__ eX,
    float* __restrict__ Z, unsigned short* __restrict__ vbw,
    float* __restrict__ out, unsigned char* smem,
    int bx, int t, int w, int mrow, int quad) {
  float* sred = (float*)smem;                  // 8 x 272 floats = 8704 B
  float* szed = (float*)(smem + 16384);        // 10 floats
  float* e_lds = (float*)(smem + 20480);       // 1152 floats = 4608 B
  const int xcd = bx & 7, j = bx >> 3;         // j: 0..19
  const int mtile = (xcd >> 1) * 4 + j / 5;    // 4 mtiles per xcd-pair
  const int c = (xcd & 1) * 5 + j % 5;         // 5 c per xcd
  const int m0 = mtile * 16;
  if (git > 0) {
    for (int idx = t; idx < 1152; idx += 512) e_lds[idx] = eX[c * 1152 + idx];
    if (t < 10) szed[t] = atomicAdd(&Z[git * 10 + t], 0.0f);  // coherent read
    __syncthreads();
  }
  const unsigned short* ap = xb + (size_t)(m0 + mrow) * K_ + w * 1152 + quad * 8;
  const unsigned short* bp = wraw + ((size_t)(w * 144 + quad) * C_ + c) * 128 + mrow * 8;
  f32x4 acc = {0.0f, 0.0f, 0.0f, 0.0f};
  if (git == 0) {
#pragma unroll 6
    for (int kk = 0; kk < 36; ++kk) {
      const bf16x8 a = *(const bf16x8*)(ap + kk * 32);
      const bf16x8 b = *(const bf16x8*)(bp + (size_t)kk * 5120);
      acc = __builtin_amdgcn_mfma_f32_16x16x32_bf16(a, b, acc, 0, 0, 0);
    }
  } else {
#pragma unroll 6
    for (int kk = 0; kk < 36; ++kk) {
      const bf16x8 a = *(const bf16x8*)(ap + kk * 32);
      const bf16x8 braw = *(const bf16x8*)(bp + (size_t)kk * 5120);
      const float ev = e_lds[w * 144 + kk * 4 + quad];  // broadcast (no conflict)
      bf16x8 b;
#pragma unroll
      for (int j8 = 0; j8 < 8; ++j8)
        b[j8] = (short)f2bf(bf2f((unsigned short)braw[j8]) * ev);
      acc = __builtin_amdgcn_mfma_f32_16x16x32_bf16(a, b, acc, 0, 0, 0);
    }
  }
#pragma unroll
  for (int rg = 0; rg < 4; ++rg)
    sred[w * 272 + mrow * 17 + quad * 4 + rg] = acc[rg];
  __syncthreads();
  if (t < 256) {
    int m, n;
    if (git == 2) { m = t >> 4; n = t & 15; } else { n = t >> 4; m = t & 15; }
    const int e = n * 17 + m;
    const float ss = ((sred[0 * 272 + e] + sred[1 * 272 + e]) +
                      (sred[2 * 272 + e] + sred[3 * 272 + e])) +
                     ((sred[4 * 272 + e] + sred[5 * 272 + e]) +
                      (sred[6 * 272 + e] + sred[7 * 272 + e]));
    const float s = (git == 0) ? ss * (1.0f / 1152.0f) : ss / szed[c];
    const float v = s * fabsf(s) / (1.0f + s * s);     // squash
    if (git == 2) out[(size_t)(m0 + m) * SCO + c * 16 + n] = v;
    else          vbw[(size_t)(c * 16 + n) * 256 + m0 + m] = f2bf(v);
  }
}

// ---------------------------------------------------------------------------
// pv phase: 144 blocks x 8 r (r1's proven geometry at 512 threads: waves 0-3
// do the MFMA m-rows, all 8 waves stage/contract). Output is ONLY the routing
// state: bvec update + e[c][r] = exp(b) + Z partial (softmax 1/Z and the
// wraw*e product are deferred to the next gemm). No wb2 materialization.
// ---------------------------------------------------------------------------
__device__ __forceinline__ void pv_phase(
    int it, const unsigned short* __restrict__ xT,
    const unsigned short* __restrict__ vbr, const float* __restrict__ W,
    const unsigned short* __restrict__ wraw_unused,
    float* __restrict__ bvec, float* __restrict__ eOut, float* __restrict__ Z,
    unsigned char* smem, int bx, int t, int lane, int w, int mrow, int quad) {
  unsigned short* svb = (unsigned short*)smem;         // 80 KB staged vb
  float* sp = (float*)smem;                            // alias: P tiles 40 KB
  float* sbs = (float*)(smem + 81920);                 // 80 floats
  const int seg = (bx & 7) * 18 + (bx >> 3);           // 0..143, XCD-swizzled
  const int r0 = seg * 8;
  bf16x8 afr[8];
  if (w < 4) {                                         // 4 waves x 16 rows = 64
    const unsigned short* ap = xT + (size_t)(seg * 64 + w * 16 + mrow) * 256 + quad * 8;
#pragma unroll
    for (int kk = 0; kk < 8; ++kk) afr[kk] = *(const bf16x8*)(ap + kk * 32);
  }
  {  // stage vb -> LDS, XOR-swizzled (all 512 threads)
    const char* src = (const char*)vbr;
    char* dst = (char*)svb;
#pragma unroll
    for (int i = 0; i < 10; ++i) {
      const int ci = i * 512 + t;
      const int lin = ci * 16;
      const int n = ci >> 5;
      *(bf16x8*)(dst + (lin ^ ((n & 7) << 4))) = *(const bf16x8*)(src + lin);
    }
  }
  __syncthreads();
  f32x4 acc[10];
  if (w < 4) {
#pragma unroll
    for (int c = 0; c < 10; ++c) acc[c] = (f32x4){0.0f, 0.0f, 0.0f, 0.0f};
#pragma unroll
    for (int c = 0; c < 10; ++c) {
      const int n = c * 16 + mrow;
      const int base = n * 512 + quad * 16;
#pragma unroll
      for (int kk = 0; kk < 8; ++kk) {
        const bf16x8 b = *(const bf16x8*)((const char*)svb +
                          ((base + kk * 64) ^ ((n & 7) << 4)));
        acc[c] = __builtin_amdgcn_mfma_f32_16x16x32_bf16(afr[kk], b, acc[c], 0, 0, 0);
      }
    }
  }
  __syncthreads();                                     // svb reads done
  if (w < 4) {
#pragma unroll
    for (int c = 0; c < 10; ++c)
#pragma unroll
      for (int rg = 0; rg < 4; ++rg) {
        const int ml = w * 16 + quad * 4 + rg;         // m = rl*8+i, 0..63
        sp[(c * 8 + (ml >> 3)) * 128 + mrow * 8 + (ml & 7)] = acc[c][rg];
      }
  }
  __syncthreads();
  const int p16 = t >> 5, l32 = t & 31;                // 16 groups of 32
#pragma unroll
  for (int ch = 0; ch < 5; ++ch) {
    const int pair = ch * 16 + p16;                    // 0..79
    const int rl = pair / 10, c = pair - rl * 10;
    const float4 pv4 = *(const float4*)&sp[(c * 8 + rl) * 128 + l32 * 4];
    const float4 wv = *(const float4*)(W + (size_t)(r0 + rl) * 1280 + c * 128 + l32 * 4);
    float prod = wv.x * pv4.x + wv.y * pv4.y + wv.z * pv4.z + wv.w * pv4.w;
    prod += __shfl_xor(prod, 1);  prod += __shfl_xor(prod, 2);
    prod += __shfl_xor(prod, 4);  prod += __shfl_xor(prod, 8);
    prod += __shfl_xor(prod, 16);
    if (l32 == 0) sbs[rl * 10 + c] = prod;
  }
  __syncthreads();
  if (t < 80) {                                        // routing update + exp
    const int rl = t / 10, c = t - rl * 10;
    const int r = r0 + rl;
    float b = sbs[t] * (1.0f / 256.0f);
    if (it != 0) b += bvec[r * C_ + c];
    bvec[r * C_ + c] = b;
    const float e = expf(b);                           // |b| << 1: safe
    sbs[t] = e;
    eOut[c * 1152 + r] = e;                            // [c][r] for gemm staging
  }
  __syncthreads();
  if (t < 10) {
    float z = 0.0f;
#pragma unroll
    for (int rl = 0; rl < 8; ++rl) z += sbs[rl * 10 + t];
    atomicAdd(&Z[(it + 1) * 10 + t], z);
  }
}

// ===========================================================================
// mega: ONE plain launch, 256 blocks x 512 threads, 82.5 KB LDS (1 block/CU).
// prep(256) -> gemm0 -> pv0 -> gemm1 -> pv1 -> gemm2. 5 barriers.
// gemm1/gemm2 B-operand = wraw x e inline -> their tile working set is
// L2-resident from gemm0 (no kernel-boundary invalidate between phases).
// ===========================================================================
__global__ __launch_bounds__(512, 1) void mega(
    const float* __restrict__ x, const float* __restrict__ W,
    float* __restrict__ out, unsigned int* __restrict__ bar,
    float* __restrict__ bvec, float* __restrict__ Z,
    float* __restrict__ eA, float* __restrict__ eB,
    unsigned short* __restrict__ xb, unsigned short* __restrict__ wraw,
    unsigned short* __restrict__ xT,
    unsigned short* __restrict__ vb0, unsigned short* __restrict__ vb1) {
  __shared__ __align__(16) unsigned char smem[82560];
  const int bx = blockIdx.x;
  const int t = threadIdx.x;
  const int lane = t & 63;
  const int w = __builtin_amdgcn_readfirstlane(t >> 6);   // 0..7
  const int mrow = lane & 15, quad = lane >> 4;

  // ---------------- ph0 prep (all 256): W->wraw; x->xb+xT; zero Z ----------
  {
    const float4* wf = (const float4*)W;                 // 368640 f4 = 1440/blk
    ushort4* wr = (ushort4*)wraw;
    for (int idx = t; idx < 1440; idx += 512) {
      const int j = bx * 1440 + idx;
      const float4 v4 = wf[j];
      ushort4 r4;
      r4.x = f2bf(v4.x); r4.y = f2bf(v4.y); r4.z = f2bf(v4.z); r4.w = f2bf(v4.w);
      wr[j] = r4;
    }
    if (bx == 0 && t < 32) Z[t] = 0.0f;
    float* sx = (float*)smem;                            // 144 x 68 floats
    const int bq = bx & 3, rseg = bx >> 2;               // one x-unit per block
    const int rbase = rseg * 18;
    for (int idx = t; idx < 64 * 36; idx += 512) {
      const int b = idx / 36, f4 = idx - b * 36;
      const size_t off = (size_t)(bq * 64 + b) * K_ + rbase * I_ + f4 * 4;
      const float4 val = *(const float4*)(x + off);
      ushort4 o4;
      o4.x = f2bf(val.x); o4.y = f2bf(val.y); o4.z = f2bf(val.z); o4.w = f2bf(val.w);
      *(ushort4*)(xb + off) = o4;
      const int rr = f4 >> 1, i4 = (f4 & 1) * 4;
      sx[(rr * 8 + i4 + 0) * 68 + b] = val.x;
      sx[(rr * 8 + i4 + 1) * 68 + b] = val.y;
      sx[(rr * 8 + i4 + 2) * 68 + b] = val.z;
      sx[(rr * 8 + i4 + 3) * 68 + b] = val.w;
    }
    __syncthreads();
    for (int row = w * 18; row < w * 18 + 18; ++row)
      xT[(size_t)(rseg * 144 + row) * 256 + bq * 64 + lane] = f2bf(sx[row * 68 + lane]);
  }
  gsync(bar, 1);

  if (bx < 160) gemm_phase(0, xb, wraw, nullptr, Z, vb0, out, smem, bx, t, w, mrow, quad);
  gsync(bar, 2);

  if (bx < 144) pv_phase(0, xT, vb0, W, wraw, bvec, eA, Z, smem, bx, t, lane, w, mrow, quad);
  gsync(bar, 3);

  if (bx < 160) gemm_phase(1, xb, wraw, eA, Z, vb1, out, smem, bx, t, w, mrow, quad);
  gsync(bar, 4);

  if (bx < 144) pv_phase(1, xT, vb1, W, wraw, bvec, eB, Z, smem, bx, t, lane, w, mrow, quad);
  gsync(bar, 5);

  if (bx < 160) gemm_phase(2, xb, wraw, eB, Z, nullptr, out, smem, bx, t, w, mrow, quad);
}

extern "C" void kernel_launch(void* const* d_in, const int* in_sizes, int n_in,
                              void* d_out, int out_size, void* d_ws, size_t ws_size,
                              hipStream_t stream) {
  const float* x = (const float*)d_in[0];  // (B,R,I) fp32
  const float* W = (const float*)d_in[1];  // (R,C,O,I) fp32
  float* out = (float*)d_out;              // (B,C,O,1) fp32

  unsigned int* bar = (unsigned int*)d_ws;                 // 4224 u32 = 16896 B
  float* bvec = (float*)d_ws + 4224;                       // 11520
  float* Z    = bvec + R_ * C_;                            // 32
  float* eA   = Z + 32;                                    // 10 x 1152
  float* eB   = eA + C_ * R_;                              // 10 x 1152
  unsigned short* xb   = (unsigned short*)(eB + C_ * R_);  // B*K
  unsigned short* wraw = xb + (size_t)B_ * K_;             // R*C*O*I
  unsigned short* xT   = wraw + (size_t)R_ * C_ * O_ * I_; // R*8*256
  unsigned short* vb0  = xT + (size_t)R_ * 8 * 256;        // 160*256
  unsigned short* vb1  = vb0 + (size_t)160 * 256;          // 160*256

  hipMemsetAsync(bar, 0, 16896, stream);                   // capture-safe
  mega<<<NB, 512, 0, stream>>>(x, W, out, bar, bvec, Z, eA, eB,
                               xb, wraw, xT, vb0, vb1);
}

// Round 9
// 136.936 us; speedup vs baseline: 1.9648x; 1.0992x over previous
//
#include <hip/hip_runtime.h>

static constexpr int B_ = 256;
static constexpr int R_ = 1152;
static constexpr int C_ = 10;
static constexpr int O_ = 16;
static constexpr int I_ = 8;
static constexpr int SCO = C_ * O_;   // 160
static constexpr int K_ = R_ * I_;    // 9216
static constexpr int NB = 256;        // grid = CU count, 1 block/CU via LDS

typedef short bf16x8 __attribute__((ext_vector_type(8)));
typedef float f32x4  __attribute__((ext_vector_type(4)));

__device__ __forceinline__ unsigned short f2bf(float f) {
  union { float f; unsigned int u; } c; c.f = f;
  const unsigned int u = c.u;
  return (unsigned short)((u + 0x7fffu + ((u >> 16) & 1u)) >> 16);  // RNE
}
__device__ __forceinline__ float bf2f(unsigned short h) {
  union { unsigned int u; float f; } c; c.u = ((unsigned int)h) << 16; return c.f;
}

// bar[] layout (u32 indices; one 64B line per 16 u32):
#define FLAG_IDX(b)    ((b) * 16)                        // 256 lines: arrival
#define REQ_IDX(k)     (4096 + (k) * 16)                 // 8 lines: flush request
#define ACK_IDX(e)     (4224 + ((e) - 1) * 16)           // 5 lines: flush acks
#define GO_IDX(k)      (4352 + (k) * 16)                 // 8 lines: go broadcast
#define RESP_IDX(e, x) (4480 + (((e) - 1) * 8 + (x)) * 16) // 5x8: responder elect
#define NBLK_IDX(x)    (5120 + (x) * 16)                 // 8 lines: blocks/XCD

// ---------------------------------------------------------------------------
// Grid barrier v3: ONE buffer_wbl2 per XCD per barrier (r8 post-mortem: r8's
// per-block RELEASE arrival = 256 wbl2/barrier, ~32 serialized per L2
// controller ~= 11 us/barrier = the 55 us residual; cf. r5->r7 where removing
// the dual per-block buffer_inv saved 57 us).
// Protocol: RELAXED arrival on own line (stores already in L2 via the
// __syncthreads drain) -> block0 detects 256 -> req broadcast -> each block
// resp-RMWs resp[epoch][real XCD via HW_REG_XCC_ID]; FIRST responder per XCD
// does ONE RELEASE RMW on ack (= wbl2 of that whole XCD: publishes every
// co-located block's stores; valid since req happens-after all arrivals) ->
// block0 waits ack == #occupied XCDs (claim counters, final by barrier-1 req
// since every block claims at kernel entry before any work) -> release-fence
// -> relaxed go. Consumers need no acquire: write-once buffers, first-touch
// reads (r7-validated). Guards degrade to wrong answer, never hang.
// ---------------------------------------------------------------------------
__device__ __forceinline__ void gsync(unsigned int* bar, unsigned int epoch,
                                      unsigned int myxcd) {
  __syncthreads();                     // drains all waves' stores into our L2
  const int bx = blockIdx.x, t = threadIdx.x;
  if (bx == 0) {
    if (t == 0)
      __hip_atomic_store(&bar[FLAG_IDX(0)], epoch,
                         __ATOMIC_RELAXED, __HIP_MEMORY_SCOPE_AGENT);
    if (t < 256) {
      int guard = 0;
      while (__hip_atomic_load(&bar[FLAG_IDX(t)],
                               __ATOMIC_RELAXED, __HIP_MEMORY_SCOPE_AGENT) < epoch) {
        __builtin_amdgcn_s_sleep(4);
        if (++guard > (1 << 18)) break;
      }
    }
    __syncthreads();                   // all 256 arrivals observed
    if (t == 0) {
      for (int k2 = 0; k2 < 8; ++k2)
        __hip_atomic_store(&bar[REQ_IDX(k2)], epoch,
                           __ATOMIC_RELAXED, __HIP_MEMORY_SCOPE_AGENT);
      const unsigned oldr = __hip_atomic_fetch_add(&bar[RESP_IDX(epoch, myxcd)], 1u,
                              __ATOMIC_RELAXED, __HIP_MEMORY_SCOPE_AGENT);
      if (oldr == 0)
        __hip_atomic_fetch_add(&bar[ACK_IDX(epoch)], 1u,
                               __ATOMIC_RELEASE, __HIP_MEMORY_SCOPE_AGENT); // wbl2
      unsigned nx = 0;
      for (int x2 = 0; x2 < 8; ++x2)
        nx += (__hip_atomic_load(&bar[NBLK_IDX(x2)],
                 __ATOMIC_RELAXED, __HIP_MEMORY_SCOPE_AGENT) > 0u) ? 1u : 0u;
      int guard = 0;
      while (__hip_atomic_load(&bar[ACK_IDX(epoch)],
                               __ATOMIC_RELAXED, __HIP_MEMORY_SCOPE_AGENT) < nx) {
        __builtin_amdgcn_s_sleep(4);
        if (++guard > (1 << 18)) break;
      }
      __builtin_amdgcn_fence(__ATOMIC_RELEASE, "agent");  // order obs -> go
      for (int k2 = 0; k2 < 8; ++k2)
        __hip_atomic_store(&bar[GO_IDX(k2)], epoch,
                           __ATOMIC_RELAXED, __HIP_MEMORY_SCOPE_AGENT);
    }
  } else {
    if (t == 0) {
      __hip_atomic_store(&bar[FLAG_IDX(bx)], epoch,
                         __ATOMIC_RELAXED, __HIP_MEMORY_SCOPE_AGENT);
      unsigned int* rq = &bar[REQ_IDX(bx & 7)];
      int guard = 0;
      while (__hip_atomic_load(rq, __ATOMIC_RELAXED,
                               __HIP_MEMORY_SCOPE_AGENT) < epoch) {
        __builtin_amdgcn_s_sleep(8);
        if (++guard > (1 << 17)) break;
      }
      const unsigned oldr = __hip_atomic_fetch_add(&bar[RESP_IDX(epoch, myxcd)], 1u,
                              __ATOMIC_RELAXED, __HIP_MEMORY_SCOPE_AGENT);
      if (oldr == 0)
        __hip_atomic_fetch_add(&bar[ACK_IDX(epoch)], 1u,
                               __ATOMIC_RELEASE, __HIP_MEMORY_SCOPE_AGENT); // wbl2
      unsigned int* g = &bar[GO_IDX(bx & 7)];
      guard = 0;
      while (__hip_atomic_load(g, __ATOMIC_RELAXED,
                               __HIP_MEMORY_SCOPE_AGENT) < epoch) {
        __builtin_amdgcn_s_sleep(16);
        if (++guard > (1 << 17)) break;
      }
    }
  }
  __syncthreads();
  asm volatile("" ::: "memory");       // compiler barrier only (r7-validated)
}

// ---------------------------------------------------------------------------
// gemm phase (VERBATIM r8): 160 blocks, (4,5) XCD tiling; B = wraw scaled
// inline by e[c][r] for git>0 (bit-identical to materialized wb2 path).
// ---------------------------------------------------------------------------
__device__ __forceinline__ void gemm_phase(
    int git, const unsigned short* __restrict__ xb,
    const unsigned short* __restrict__ wraw, const float* __restrict__ eX,
    float* __restrict__ Z, unsigned short* __restrict__ vbw,
    float* __restrict__ out, unsigned char* smem,
    int bx, int t, int w, int mrow, int quad) {
  float* sred = (float*)smem;                  // 8 x 272 floats
  float* szed = (float*)(smem + 16384);        // 10 floats
  float* e_lds = (float*)(smem + 20480);       // 1152 floats
  const int xcd = bx & 7, j = bx >> 3;         // j: 0..19
  const int mtile = (xcd >> 1) * 4 + j / 5;
  const int c = (xcd & 1) * 5 + j % 5;
  const int m0 = mtile * 16;
  if (git > 0) {
    for (int idx = t; idx < 1152; idx += 512) e_lds[idx] = eX[c * 1152 + idx];
    if (t < 10) szed[t] = atomicAdd(&Z[git * 10 + t], 0.0f);  // coherent read
    __syncthreads();
  }
  const unsigned short* ap = xb + (size_t)(m0 + mrow) * K_ + w * 1152 + quad * 8;
  const unsigned short* bp = wraw + ((size_t)(w * 144 + quad) * C_ + c) * 128 + mrow * 8;
  f32x4 acc = {0.0f, 0.0f, 0.0f, 0.0f};
  if (git == 0) {
#pragma unroll 6
    for (int kk = 0; kk < 36; ++kk) {
      const bf16x8 a = *(const bf16x8*)(ap + kk * 32);
      const bf16x8 b = *(const bf16x8*)(bp + (size_t)kk * 5120);
      acc = __builtin_amdgcn_mfma_f32_16x16x32_bf16(a, b, acc, 0, 0, 0);
    }
  } else {
#pragma unroll 6
    for (int kk = 0; kk < 36; ++kk) {
      const bf16x8 a = *(const bf16x8*)(ap + kk * 32);
      const bf16x8 braw = *(const bf16x8*)(bp + (size_t)kk * 5120);
      const float ev = e_lds[w * 144 + kk * 4 + quad];  // broadcast
      bf16x8 b;
#pragma unroll
      for (int j8 = 0; j8 < 8; ++j8)
        b[j8] = (short)f2bf(bf2f((unsigned short)braw[j8]) * ev);
      acc = __builtin_amdgcn_mfma_f32_16x16x32_bf16(a, b, acc, 0, 0, 0);
    }
  }
#pragma unroll
  for (int rg = 0; rg < 4; ++rg)
    sred[w * 272 + mrow * 17 + quad * 4 + rg] = acc[rg];
  __syncthreads();
  if (t < 256) {
    int m, n;
    if (git == 2) { m = t >> 4; n = t & 15; } else { n = t >> 4; m = t & 15; }
    const int e = n * 17 + m;
    const float ss = ((sred[0 * 272 + e] + sred[1 * 272 + e]) +
                      (sred[2 * 272 + e] + sred[3 * 272 + e])) +
                     ((sred[4 * 272 + e] + sred[5 * 272 + e]) +
                      (sred[6 * 272 + e] + sred[7 * 272 + e]));
    const float s = (git == 0) ? ss * (1.0f / 1152.0f) : ss / szed[c];
    const float v = s * fabsf(s) / (1.0f + s * s);     // squash
    if (git == 2) out[(size_t)(m0 + m) * SCO + c * 16 + n] = v;
    else          vbw[(size_t)(c * 16 + n) * 256 + m0 + m] = f2bf(v);
  }
}

// ---------------------------------------------------------------------------
// pv phase (VERBATIM r8): 144 blocks x 8 r; emits bvec update + e[c][r] +
// Z partials only (scaled-W product deferred to next gemm).
// ---------------------------------------------------------------------------
__device__ __forceinline__ void pv_phase(
    int it, const unsigned short* __restrict__ xT,
    const unsigned short* __restrict__ vbr, const float* __restrict__ W,
    float* __restrict__ bvec, float* __restrict__ eOut, float* __restrict__ Z,
    unsigned char* smem, int bx, int t, int w, int mrow, int quad) {
  unsigned short* svb = (unsigned short*)smem;         // 80 KB staged vb
  float* sp = (float*)smem;                            // alias: P tiles
  float* sbs = (float*)(smem + 81920);                 // 80 floats
  const int seg = (bx & 7) * 18 + (bx >> 3);           // 0..143, XCD-swizzled
  const int r0 = seg * 8;
  bf16x8 afr[8];
  if (w < 4) {
    const unsigned short* ap = xT + (size_t)(seg * 64 + w * 16 + mrow) * 256 + quad * 8;
#pragma unroll
    for (int kk = 0; kk < 8; ++kk) afr[kk] = *(const bf16x8*)(ap + kk * 32);
  }
  {  // stage vb -> LDS, XOR-swizzled
    const char* src = (const char*)vbr;
    char* dst = (char*)svb;
#pragma unroll
    for (int i = 0; i < 10; ++i) {
      const int ci = i * 512 + t;
      const int lin = ci * 16;
      const int n = ci >> 5;
      *(bf16x8*)(dst + (lin ^ ((n & 7) << 4))) = *(const bf16x8*)(src + lin);
    }
  }
  __syncthreads();
  f32x4 acc[10];
  if (w < 4) {
#pragma unroll
    for (int c = 0; c < 10; ++c) acc[c] = (f32x4){0.0f, 0.0f, 0.0f, 0.0f};
#pragma unroll
    for (int c = 0; c < 10; ++c) {
      const int n = c * 16 + mrow;
      const int base = n * 512 + quad * 16;
#pragma unroll
      for (int kk = 0; kk < 8; ++kk) {
        const bf16x8 b = *(const bf16x8*)((const char*)svb +
                          ((base + kk * 64) ^ ((n & 7) << 4)));
        acc[c] = __builtin_amdgcn_mfma_f32_16x16x32_bf16(afr[kk], b, acc[c], 0, 0, 0);
      }
    }
  }
  __syncthreads();
  if (w < 4) {
#pragma unroll
    for (int c = 0; c < 10; ++c)
#pragma unroll
      for (int rg = 0; rg < 4; ++rg) {
        const int ml = w * 16 + quad * 4 + rg;         // m = rl*8+i, 0..63
        sp[(c * 8 + (ml >> 3)) * 128 + mrow * 8 + (ml & 7)] = acc[c][rg];
      }
  }
  __syncthreads();
  const int p16 = t >> 5, l32 = t & 31;
#pragma unroll
  for (int ch = 0; ch < 5; ++ch) {
    const int pair = ch * 16 + p16;                    // 0..79
    const int rl = pair / 10, c = pair - rl * 10;
    const float4 pv4 = *(const float4*)&sp[(c * 8 + rl) * 128 + l32 * 4];
    const float4 wv = *(const float4*)(W + (size_t)(r0 + rl) * 1280 + c * 128 + l32 * 4);
    float prod = wv.x * pv4.x + wv.y * pv4.y + wv.z * pv4.z + wv.w * pv4.w;
    prod += __shfl_xor(prod, 1);  prod += __shfl_xor(prod, 2);
    prod += __shfl_xor(prod, 4);  prod += __shfl_xor(prod, 8);
    prod += __shfl_xor(prod, 16);
    if (l32 == 0) sbs[rl * 10 + c] = prod;
  }
  __syncthreads();
  if (t < 80) {                                        // routing update + exp
    const int rl = t / 10, c = t - rl * 10;
    const int r = r0 + rl;
    float b = sbs[t] * (1.0f / 256.0f);
    if (it != 0) b += bvec[r * C_ + c];
    bvec[r * C_ + c] = b;
    const float e = expf(b);                           // |b| << 1: safe
    sbs[t] = e;
    eOut[c * 1152 + r] = e;
  }
  __syncthreads();
  if (t < 10) {
    float z = 0.0f;
#pragma unroll
    for (int rl = 0; rl < 8; ++rl) z += sbs[rl * 10 + t];
    atomicAdd(&Z[(it + 1) * 10 + t], z);
  }
}

// ===========================================================================
// mega: ONE plain launch, 256 blocks x 512 threads, 82.5 KB LDS (1 block/CU).
// prep(256) -> gemm0 -> pv0 -> gemm1 -> pv1 -> gemm2. Phases VERBATIM r8;
// only the barrier changed (XCD-leader flush). Claim NBLK[myxcd] at entry
// (completes before barrier-1 arrival via gsync's opening __syncthreads).
// ===========================================================================
__global__ __launch_bounds__(512, 1) void mega(
    const float* __restrict__ x, const float* __restrict__ W,
    float* __restrict__ out, unsigned int* __restrict__ bar,
    float* __restrict__ bvec, float* __restrict__ Z,
    float* __restrict__ eA, float* __restrict__ eB,
    unsigned short* __restrict__ xb, unsigned short* __restrict__ wraw,
    unsigned short* __restrict__ xT,
    unsigned short* __restrict__ vb0, unsigned short* __restrict__ vb1) {
  __shared__ __align__(16) unsigned char smem[82560];
  const int bx = blockIdx.x;
  const int t = threadIdx.x;
  const int lane = t & 63;
  const int w = __builtin_amdgcn_readfirstlane(t >> 6);   // 0..7
  const int mrow = lane & 15, quad = lane >> 4;

  unsigned int myxcd;
  asm volatile("s_getreg_b32 %0, hwreg(HW_REG_XCC_ID)" : "=s"(myxcd));
  myxcd &= 7u;
  if (t == 0)    // claim: blocks-per-XCD census (final before barrier-1 req)
    __hip_atomic_fetch_add(&bar[NBLK_IDX(myxcd)], 1u,
                           __ATOMIC_RELAXED, __HIP_MEMORY_SCOPE_AGENT);
  if (bx == 0 && t < 32) Z[t] = 0.0f;

  // ---------------- ph0 prep (all 256): W->wraw; x->xb+xT ------------------
  {
    const float4* wf = (const float4*)W;                 // 368640 f4 = 1440/blk
    ushort4* wr = (ushort4*)wraw;
    for (int idx = t; idx < 1440; idx += 512) {
      const int j = bx * 1440 + idx;
      const float4 v4 = wf[j];
      ushort4 r4;
      r4.x = f2bf(v4.x); r4.y = f2bf(v4.y); r4.z = f2bf(v4.z); r4.w = f2bf(v4.w);
      wr[j] = r4;
    }
    float* sx = (float*)smem;                            // 144 x 68 floats
    const int bq = bx & 3, rseg = bx >> 2;
    const int rbase = rseg * 18;
    for (int idx = t; idx < 64 * 36; idx += 512) {
      const int b = idx / 36, f4 = idx - b * 36;
      const size_t off = (size_t)(bq * 64 + b) * K_ + rbase * I_ + f4 * 4;
      const float4 val = *(const float4*)(x + off);
      ushort4 o4;
      o4.x = f2bf(val.x); o4.y = f2bf(val.y); o4.z = f2bf(val.z); o4.w = f2bf(val.w);
      *(ushort4*)(xb + off) = o4;
      const int rr = f4 >> 1, i4 = (f4 & 1) * 4;
      sx[(rr * 8 + i4 + 0) * 68 + b] = val.x;
      sx[(rr * 8 + i4 + 1) * 68 + b] = val.y;
      sx[(rr * 8 + i4 + 2) * 68 + b] = val.z;
      sx[(rr * 8 + i4 + 3) * 68 + b] = val.w;
    }
    __syncthreads();
    for (int row = w * 18; row < w * 18 + 18; ++row)
      xT[(size_t)(rseg * 144 + row) * 256 + bq * 64 + lane] = f2bf(sx[row * 68 + lane]);
  }
  gsync(bar, 1, myxcd);

  if (bx < 160) gemm_phase(0, xb, wraw, nullptr, Z, vb0, out, smem, bx, t, w, mrow, quad);
  gsync(bar, 2, myxcd);

  if (bx < 144) pv_phase(0, xT, vb0, W, bvec, eA, Z, smem, bx, t, w, mrow, quad);
  gsync(bar, 3, myxcd);

  if (bx < 160) gemm_phase(1, xb, wraw, eA, Z, vb1, out, smem, bx, t, w, mrow, quad);
  gsync(bar, 4, myxcd);

  if (bx < 144) pv_phase(1, xT, vb1, W, bvec, eB, Z, smem, bx, t, w, mrow, quad);
  gsync(bar, 5, myxcd);

  if (bx < 160) gemm_phase(2, xb, wraw, eB, Z, nullptr, out, smem, bx, t, w, mrow, quad);
}

extern "C" void kernel_launch(void* const* d_in, const int* in_sizes, int n_in,
                              void* d_out, int out_size, void* d_ws, size_t ws_size,
                              hipStream_t stream) {
  const float* x = (const float*)d_in[0];  // (B,R,I) fp32
  const float* W = (const float*)d_in[1];  // (R,C,O,I) fp32
  float* out = (float*)d_out;              // (B,C,O,1) fp32

  unsigned int* bar = (unsigned int*)d_ws;                 // 5376 u32 = 21504 B
  float* bvec = (float*)d_ws + 5376;                       // 11520
  float* Z    = bvec + R_ * C_;                            // 32
  float* eA   = Z + 32;                                    // 10 x 1152
  float* eB   = eA + C_ * R_;                              // 10 x 1152
  unsigned short* xb   = (unsigned short*)(eB + C_ * R_);  // B*K
  unsigned short* wraw = xb + (size_t)B_ * K_;             // R*C*O*I
  unsigned short* xT   = wraw + (size_t)R_ * C_ * O_ * I_; // R*8*256
  unsigned short* vb0  = xT + (size_t)R_ * 8 * 256;        // 160*256
  unsigned short* vb1  = vb0 + (size_t)160 * 256;          // 160*256

  hipMemsetAsync(bar, 0, 21504, stream);                   // capture-safe
  mega<<<NB, 512, 0, stream>>>(x, W, out, bar, bvec, Z, eA, eB,
                               xb, wraw, xT, vb0, vb1);
}